// Round 1
// baseline (101.826 us; speedup 1.0000x reference)
//
#include <hip/hip_runtime.h>
#include <math.h>

#define BB 64
#define NN 2000
#define HH 128
#define NHEAD 8
#define SPLIT 8          // k2 row splits per batch
#define RROWS (NN/SPLIT) // 250
#define SPLIT4 4         // k4 row splits per batch
#define R4 (NN/SPLIT4)   // 500

// ws layout (float offsets)
#define OFF_QK   0                         // B*8*128   = 65536
#define OFF_M    (OFF_QK + BB*NHEAD*HH)    // B*8*8     = 4096
#define OFF_L    (OFF_M + BB*SPLIT*NHEAD)  // 4096
#define OFF_W    (OFF_L + BB*SPLIT*NHEAD)  // B*8*8*128 = 524288
#define OFF_LQ   (OFF_W + BB*SPLIT*NHEAD*HH) // B*128
#define OFF_T    (OFF_LQ + BB*HH)          // B*N = 128000
#define OFF_PMAX (OFF_T + BB*NN)           // B*4

// ---------------- K1: glimpse_q and qk[b][h][j] ----------------
__global__ __launch_bounds__(128) void k1_prep(
    const float* __restrict__ pe, const float* __restrict__ cls,
    const float* __restrict__ Wqg, const float* __restrict__ Wqf,
    const float* __restrict__ Wql, const float* __restrict__ Wk,
    const int* __restrict__ lp, float* __restrict__ qk_out) {
  __shared__ float sc[HH], sl[HH], q[HH];
  int b = blockIdx.x, t = threadIdx.x;
  int last = lp[b];
  sc[t] = cls[b*HH + t];
  sl[t] = pe[((long)b*NN + last)*HH + t];
  __syncthreads();
  float acc = 0.f;
  for (int j = 0; j < HH; j++)
    acc += Wqg[t*HH+j]*sc[j] + (Wqf[t*HH+j] + Wql[t*HH+j])*sl[j];
  q[t] = acc;
  __syncthreads();
  for (int h = 0; h < NHEAD; h++) {
    float a = 0.f;
    for (int d = 0; d < 16; d++)
      a += q[h*16+d] * Wk[(h*16+d)*HH + t];
    qk_out[(b*NHEAD + h)*HH + t] = a * 0.25f;   // fold 1/sqrt(head_dim)
  }
}

// ---------------- K2: flash-style decode attention, split over rows ----------------
__global__ __launch_bounds__(256) void k2_attn(
    const float* __restrict__ pe, const float* __restrict__ qk,
    const int* __restrict__ lp,
    float* __restrict__ mout, float* __restrict__ lout, float* __restrict__ Wout) {
  int b = blockIdx.y, sp = blockIdx.x, tid = threadIdx.x;
  __shared__ float qks[NHEAD][HH];
  __shared__ float plds[256][9];        // +1 pad: write bank-conflict-free
  __shared__ float red[NHEAD][4];
  __shared__ float wtmp[NHEAD][HH];
  for (int i = tid; i < NHEAD*HH; i += 256) qks[i>>7][i&127] = qk[b*NHEAD*HH + i];
  __syncthreads();

  int n = sp*RROWS + tid;
  bool valid = (tid < RROWS);
  float s[NHEAD];
  #pragma unroll
  for (int h = 0; h < NHEAD; h++) s[h] = -INFINITY;
  if (valid) {
    const float4* row = (const float4*)(pe + ((long)(b*NN + n))*HH);
    #pragma unroll
    for (int h = 0; h < NHEAD; h++) s[h] = 0.f;
    for (int c = 0; c < 32; c++) {
      float4 p4 = row[c];
      #pragma unroll
      for (int h = 0; h < NHEAD; h++) {
        float4 k4 = ((const float4*)qks[h])[c];
        s[h] += p4.x*k4.x + p4.y*k4.y + p4.z*k4.z + p4.w*k4.w;
      }
    }
    if (n == lp[b]) {
      #pragma unroll
      for (int h = 0; h < NHEAD; h++) s[h] += -1e9f;
    }
  }
  int lane = tid & 63, wid = tid >> 6;
  float m[NHEAD], l[NHEAD], p[NHEAD];
  #pragma unroll
  for (int h = 0; h < NHEAD; h++) {
    float v = s[h];
    for (int off = 32; off; off >>= 1) v = fmaxf(v, __shfl_xor(v, off));
    if (lane == 0) red[h][wid] = v;
  }
  __syncthreads();
  #pragma unroll
  for (int h = 0; h < NHEAD; h++)
    m[h] = fmaxf(fmaxf(red[h][0], red[h][1]), fmaxf(red[h][2], red[h][3]));
  __syncthreads();                      // red reused below
  #pragma unroll
  for (int h = 0; h < NHEAD; h++) {
    p[h] = valid ? expf(s[h] - m[h]) : 0.f;
    plds[tid][h] = p[h];
    float v = p[h];
    for (int off = 32; off; off >>= 1) v += __shfl_xor(v, off);
    if (lane == 0) red[h][wid] = v;
  }
  __syncthreads();
  #pragma unroll
  for (int h = 0; h < NHEAD; h++) l[h] = red[h][0] + red[h][1] + red[h][2] + red[h][3];

  // phase 2: W[h][j] = sum_n p[n][h] * pe[n][j]; two row-halves over thread groups
  int j = tid & 127, g = tid >> 7;
  int nlo = g ? RROWS/2 : 0, nhi = g ? RROWS : RROWS/2;
  float wacc[NHEAD];
  #pragma unroll
  for (int h = 0; h < NHEAD; h++) wacc[h] = 0.f;
  const float* peb = pe + ((long)b*NN + sp*RROWS)*HH;
  for (int nn2 = nlo; nn2 < nhi; nn2++) {
    float pv = peb[nn2*HH + j];
    #pragma unroll
    for (int h = 0; h < NHEAD; h++) wacc[h] += plds[nn2][h] * pv;
  }
  if (g == 0) {
    #pragma unroll
    for (int h = 0; h < NHEAD; h++) wtmp[h][j] = wacc[h];
  }
  __syncthreads();
  if (g == 1) {
    float* Wp = Wout + (long)((b*SPLIT + sp)*NHEAD)*HH;
    #pragma unroll
    for (int h = 0; h < NHEAD; h++) Wp[h*HH + j] = wtmp[h][j] + wacc[h];
  }
  if (tid < NHEAD)            mout[(b*SPLIT + sp)*NHEAD + tid] = m[tid];
  else if (tid < 2*NHEAD)     lout[(b*SPLIT + sp)*NHEAD + (tid - NHEAD)] = l[tid - NHEAD];
}

// ---------------- K3: combine splits, small matvecs, produce lq[b] ----------------
__global__ __launch_bounds__(128) void k3_combine(
    const float* __restrict__ mpart, const float* __restrict__ lpart,
    const float* __restrict__ Wpart, const float* __restrict__ Wv,
    const float* __restrict__ Wc, const float* __restrict__ bc,
    const float* __restrict__ lWk, float* __restrict__ lq_out) {
  int b = blockIdx.x, t = threadIdx.x;
  __shared__ float scale[SPLIT][NHEAD];
  __shared__ float Ls[NHEAD];
  __shared__ float Wn[NHEAD][HH], outf[HH], fq[HH];
  if (t < NHEAD) {
    int h = t;
    float mm = -INFINITY;
    for (int s = 0; s < SPLIT; s++) mm = fmaxf(mm, mpart[(b*SPLIT + s)*NHEAD + h]);
    float ll = 0.f;
    for (int s = 0; s < SPLIT; s++) {
      float e = expf(mpart[(b*SPLIT + s)*NHEAD + h] - mm);
      scale[s][h] = e;
      ll += lpart[(b*SPLIT + s)*NHEAD + h] * e;
    }
    Ls[h] = ll;
  }
  __syncthreads();
  for (int h = 0; h < NHEAD; h++) {
    float a = 0.f;
    for (int s = 0; s < SPLIT; s++)
      a += Wpart[(long)((b*SPLIT + s)*NHEAD + h)*HH + t] * scale[s][h];
    Wn[h][t] = a / Ls[h];
  }
  __syncthreads();
  {
    int h = t >> 4;
    float a = 0.f;
    for (int jj = 0; jj < HH; jj++) a += Wv[t*HH + jj] * Wn[h][jj];
    outf[t] = a;
  }
  __syncthreads();
  {
    float a = bc[t];
    for (int k = 0; k < HH; k++) a += Wc[t*HH + k] * outf[k];
    fq[t] = a;
  }
  __syncthreads();
  {
    float a = 0.f;
    for (int i = 0; i < HH; i++) a += fq[i] * lWk[i*HH + t];
    lq_out[b*HH + t] = a * 0.08838834764831845f;  // 1/sqrt(128)
  }
}

// ---------------- K4: pointer logits t[b][n] + partial max ----------------
__global__ __launch_bounds__(256) void k4_logits(
    const float* __restrict__ pe, const float* __restrict__ lq,
    const int* __restrict__ lp, float* __restrict__ tout, float* __restrict__ pmax) {
  int b = blockIdx.y, sp = blockIdx.x, tid = threadIdx.x;
  __shared__ float lqs[HH];
  __shared__ float red[4];
  if (tid < HH) lqs[tid] = lq[b*HH + tid];
  __syncthreads();
  int last = lp[b];
  float mx = -INFINITY;
  for (int r = 0; r < 2; r++) {
    int n = sp*R4 + tid + r*256;
    if (n < (sp+1)*R4) {
      const float4* row = (const float4*)(pe + ((long)(b*NN + n))*HH);
      float acc = 0.f;
      for (int c = 0; c < 32; c++) {
        float4 p4 = row[c];
        float4 k4 = ((const float4*)lqs)[c];
        acc += p4.x*k4.x + p4.y*k4.y + p4.z*k4.z + p4.w*k4.w;
      }
      float tv = 10.f * tanhf(acc);
      if (n == last) tv += -1e9f;
      tout[b*NN + n] = tv;
      mx = fmaxf(mx, tv);
    }
  }
  int lane = tid & 63, wid = tid >> 6;
  for (int off = 32; off; off >>= 1) mx = fmaxf(mx, __shfl_xor(mx, off));
  if (lane == 0) red[wid] = mx;
  __syncthreads();
  if (tid == 0)
    pmax[b*SPLIT4 + sp] = fmaxf(fmaxf(red[0], red[1]), fmaxf(red[2], red[3]));
}

// ---------------- K5: final softmax over N ----------------
__global__ __launch_bounds__(256) void k5_softmax(
    const float* __restrict__ tout, const float* __restrict__ pmax,
    float* __restrict__ out) {
  int b = blockIdx.x, tid = threadIdx.x;
  __shared__ float red[4];
  __shared__ float Msh, Lsh;
  if (tid == 0)
    Msh = fmaxf(fmaxf(pmax[b*SPLIT4+0], pmax[b*SPLIT4+1]),
                fmaxf(pmax[b*SPLIT4+2], pmax[b*SPLIT4+3]));
  __syncthreads();
  float M = Msh;
  float sum = 0.f;
  for (int n = tid; n < NN; n += 256) sum += expf(tout[b*NN + n] - M);
  int lane = tid & 63, wid = tid >> 6;
  for (int off = 32; off; off >>= 1) sum += __shfl_xor(sum, off);
  if (lane == 0) red[wid] = sum;
  __syncthreads();
  if (tid == 0) Lsh = red[0] + red[1] + red[2] + red[3];
  __syncthreads();
  float inv = 1.f / Lsh;
  for (int n = tid; n < NN; n += 256) out[b*NN + n] = expf(tout[b*NN + n] - M) * inv;
}

extern "C" void kernel_launch(void* const* d_in, const int* in_sizes, int n_in,
                              void* d_out, int out_size, void* d_ws, size_t ws_size,
                              hipStream_t stream) {
  const float* pe   = (const float*)d_in[0];
  const float* cls  = (const float*)d_in[1];
  const float* Wqg  = (const float*)d_in[2];
  const float* Wqf  = (const float*)d_in[3];
  const float* Wql  = (const float*)d_in[4];
  const float* Wk   = (const float*)d_in[5];
  const float* Wv   = (const float*)d_in[6];
  const float* lWk  = (const float*)d_in[7];
  const float* Wc   = (const float*)d_in[8];
  const float* bc   = (const float*)d_in[9];
  const int*   lp   = (const int*)d_in[10];
  float* out = (float*)d_out;
  float* ws  = (float*)d_ws;

  float* qk    = ws + OFF_QK;
  float* mpart = ws + OFF_M;
  float* lpart = ws + OFF_L;
  float* Wpart = ws + OFF_W;
  float* lq    = ws + OFF_LQ;
  float* tbuf  = ws + OFF_T;
  float* pmax  = ws + OFF_PMAX;

  k1_prep<<<dim3(BB), dim3(128), 0, stream>>>(pe, cls, Wqg, Wqf, Wql, Wk, lp, qk);
  k2_attn<<<dim3(SPLIT, BB), dim3(256), 0, stream>>>(pe, qk, lp, mpart, lpart, Wpart);
  k3_combine<<<dim3(BB), dim3(128), 0, stream>>>(mpart, lpart, Wpart, Wv, Wc, bc, lWk, lq);
  k4_logits<<<dim3(SPLIT4, BB), dim3(256), 0, stream>>>(pe, lq, lp, tbuf, pmax);
  k5_softmax<<<dim3(BB), dim3(256), 0, stream>>>(tbuf, pmax, out);
}

// Round 2
// 66.695 us; speedup vs baseline: 1.5267x; 1.5267x over previous
//
#include <hip/hip_runtime.h>
#include <math.h>

#define BB 64
#define NN 2000
#define HH 128
#define NHEAD 8

// ---------------- K1: glimpse_q and qk[b][h][j] (scale 1/4 folded) ----------------
__global__ __launch_bounds__(128) void k1_prep(
    const float* __restrict__ pe, const float* __restrict__ cls,
    const float* __restrict__ Wqg, const float* __restrict__ Wqf,
    const float* __restrict__ Wql, const float* __restrict__ Wk,
    const int* __restrict__ lp, float* __restrict__ qk_out) {
  __shared__ float sc[HH], sl[HH], q[HH];
  int b = blockIdx.x, t = threadIdx.x;
  int last = lp[b];
  sc[t] = cls[b*HH + t];
  sl[t] = pe[((long)b*NN + last)*HH + t];
  __syncthreads();
  float acc = 0.f;
  for (int j = 0; j < HH; j++)
    acc += Wqg[t*HH+j]*sc[j] + (Wqf[t*HH+j] + Wql[t*HH+j])*sl[j];
  q[t] = acc;
  __syncthreads();
  for (int h = 0; h < NHEAD; h++) {
    float a = 0.f;
    for (int d = 0; d < 16; d++)
      a += q[h*16+d] * Wk[(h*16+d)*HH + t];
    qk_out[(b*NHEAD + h)*HH + t] = a * 0.25f;
  }
}

// ---------------- K2: single-logical-pass attention, no-max split softmax ----------------
// grid (splits, B), 256 threads. 8 threads per row, 2 rows per thread per iter.
__global__ __launch_bounds__(256) void k2_attn(
    const float* __restrict__ pe, const float* __restrict__ qk,
    const int* __restrict__ lp, float* __restrict__ lout, float* __restrict__ Wout,
    int splits, int rpb) {
  int b = blockIdx.y, sp = blockIdx.x, tid = threadIdx.x;
  __shared__ float4 smem4[1032];          // [0..255]=qks4, [256..383]=plds4; aliased by wred
  float4* qks4  = smem4;                  // [8][32] float4
  float4* plds4 = smem4 + 256;            // [64 slots][2] float4
  float*  smem  = (float*)smem4;

  const float4* qkg = (const float4*)(qk + b*NHEAD*HH);
  if (tid < 256) qks4[tid] = qkg[tid];
  __syncthreads();

  int last = lp[b];
  int r0 = sp * rpb;
  int r1 = min(r0 + rpb, NN);
  int r = tid >> 3, o = tid & 7;
  int w = tid >> 6, lane = tid & 63;

  float wacc[NHEAD][2];
  float lacc[NHEAD];
  #pragma unroll
  for (int h = 0; h < NHEAD; h++) { wacc[h][0]=0.f; wacc[h][1]=0.f; lacc[h]=0.f; }

  const float4* peg = (const float4*)pe;

  for (int base = r0; base < r1; base += 64) {
    // ---- phase A: dots for rows (base+r) and (base+32+r) ----
    int nA = base + r;
    int nB = base + 32 + r;
    bool vA = nA < r1, vB = nB < r1;
    long offA = (long)(b*NN + (vA ? nA : r1-1)) * 32;   // in float4 units
    long offB = (long)(b*NN + (vB ? nB : r1-1)) * 32;
    float4 a4[4], b4[4];
    #pragma unroll
    for (int t = 0; t < 4; t++) {
      a4[t] = peg[offA + o + 8*t];
      b4[t] = peg[offB + o + 8*t];
    }
    float sA[NHEAD], sB[NHEAD];
    #pragma unroll
    for (int h = 0; h < NHEAD; h++) {
      float accA = 0.f, accB = 0.f;
      #pragma unroll
      for (int t = 0; t < 4; t++) {
        float4 k4 = qks4[h*32 + o + 8*t];
        accA += a4[t].x*k4.x + a4[t].y*k4.y + a4[t].z*k4.z + a4[t].w*k4.w;
        accB += b4[t].x*k4.x + b4[t].y*k4.y + b4[t].z*k4.z + b4[t].w*k4.w;
      }
      sA[h] = accA; sB[h] = accB;
    }
    #pragma unroll
    for (int h = 0; h < NHEAD; h++) {
      #pragma unroll
      for (int d = 1; d < 8; d <<= 1) {
        sA[h] += __shfl_xor(sA[h], d);
        sB[h] += __shfl_xor(sB[h], d);
      }
    }
    bool mA = vA && (nA != last), mB = vB && (nB != last);
    if (o == 0) {
      float4 pa0, pa1, pb0, pb1;
      pa0.x = mA ? __expf(sA[0]) : 0.f; pa0.y = mA ? __expf(sA[1]) : 0.f;
      pa0.z = mA ? __expf(sA[2]) : 0.f; pa0.w = mA ? __expf(sA[3]) : 0.f;
      pa1.x = mA ? __expf(sA[4]) : 0.f; pa1.y = mA ? __expf(sA[5]) : 0.f;
      pa1.z = mA ? __expf(sA[6]) : 0.f; pa1.w = mA ? __expf(sA[7]) : 0.f;
      pb0.x = mB ? __expf(sB[0]) : 0.f; pb0.y = mB ? __expf(sB[1]) : 0.f;
      pb0.z = mB ? __expf(sB[2]) : 0.f; pb0.w = mB ? __expf(sB[3]) : 0.f;
      pb1.x = mB ? __expf(sB[4]) : 0.f; pb1.y = mB ? __expf(sB[5]) : 0.f;
      pb1.z = mB ? __expf(sB[6]) : 0.f; pb1.w = mB ? __expf(sB[7]) : 0.f;
      plds4[r*2+0] = pa0; plds4[r*2+1] = pa1;
      plds4[(32+r)*2+0] = pb0; plds4[(32+r)*2+1] = pb1;
    }
    __syncthreads();

    // ---- phase B: weighted accumulate, wave-private rows ----
    #pragma unroll 4
    for (int i = 0; i < 16; i++) {
      int s = w*8 + (i&7) + ((i>>3)<<5);       // slots w*8..+7 and 32+w*8..+7
      int n = base + s;
      long off = (long)(b*NN + min(n, NN-1)) * HH;
      float v0 = pe[off + lane];
      float v1 = pe[off + 64 + lane];
      float4 plo = plds4[s*2], phi = plds4[s*2+1];
      float pl[NHEAD] = {plo.x, plo.y, plo.z, plo.w, phi.x, phi.y, phi.z, phi.w};
      #pragma unroll
      for (int h = 0; h < NHEAD; h++) {
        wacc[h][0] += pl[h]*v0;
        wacc[h][1] += pl[h]*v1;
        lacc[h]    += pl[h];
      }
    }
    __syncthreads();   // protect plds reuse next iteration (multi-iter fallback)
  }

  // ---- cross-wave reduction (wred aliases qks/plds) ----
  #pragma unroll
  for (int h = 0; h < NHEAD; h++) {
    smem[w*1024 + h*HH + lane]      = wacc[h][0];
    smem[w*1024 + h*HH + 64 + lane] = wacc[h][1];
  }
  if (lane == 0) {
    #pragma unroll
    for (int h = 0; h < NHEAD; h++) smem[4096 + w*NHEAD + h] = lacc[h];
  }
  __syncthreads();
  int h2 = tid >> 5, j4 = tid & 31;
  float4 sum = smem4[h2*32 + j4];
  float4 s1 = smem4[256 + h2*32 + j4];
  float4 s2 = smem4[512 + h2*32 + j4];
  float4 s3 = smem4[768 + h2*32 + j4];
  sum.x += s1.x + s2.x + s3.x; sum.y += s1.y + s2.y + s3.y;
  sum.z += s1.z + s2.z + s3.z; sum.w += s1.w + s2.w + s3.w;
  float4* Wo = (float4*)(Wout + ((long)(b*splits + sp)*NHEAD + h2)*HH);
  Wo[j4] = sum;
  if (tid < NHEAD)
    lout[(b*splits + sp)*NHEAD + tid] =
        smem[4096+tid] + smem[4096+8+tid] + smem[4096+16+tid] + smem[4096+24+tid];
}

// ---------------- K3a: reduce W partials over splits ----------------
__global__ __launch_bounds__(128) void k3a(
    const float* __restrict__ lpart, const float* __restrict__ Wpart,
    float* __restrict__ Wn, int splits) {
  int b = blockIdx.x, h = blockIdx.y, t = threadIdx.x;
  float acc = 0.f, ls = 0.f;
  #pragma unroll 4
  for (int s = 0; s < splits; s++) {
    acc += Wpart[((long)(b*splits+s)*NHEAD + h)*HH + t];
    ls  += lpart[(b*splits+s)*NHEAD + h];
  }
  Wn[(b*NHEAD+h)*HH + t] = acc / ls;
}

// ---------------- K3b: small matvec chain -> lq ----------------
__global__ __launch_bounds__(128) void k3b(
    const float* __restrict__ Wn, const float* __restrict__ Wv,
    const float* __restrict__ Wc, const float* __restrict__ bc,
    const float* __restrict__ lWk, float* __restrict__ lq_out) {
  int b = blockIdx.x, t = threadIdx.x;
  __shared__ float Wns[NHEAD*HH], outf[HH], fq[HH];
  for (int i = t; i < NHEAD*HH; i += 128) Wns[i] = Wn[b*NHEAD*HH + i];
  __syncthreads();
  {
    int h = t >> 4;
    float a = 0.f;
    for (int j = 0; j < HH; j++) a += Wv[t*HH+j] * Wns[h*HH+j];
    outf[t] = a;
  }
  __syncthreads();
  {
    float a = bc[t];
    for (int k = 0; k < HH; k++) a += Wc[t*HH+k] * outf[k];
    fq[t] = a;
  }
  __syncthreads();
  {
    float a = 0.f;
    for (int i = 0; i < HH; i++) a += fq[i] * lWk[i*HH+t];
    lq_out[b*HH+t] = a * 0.08838834764831845f;   // 1/sqrt(128)
  }
}

// ---------------- K4: pointer logits -> exp(t-10) + partial sums ----------------
__global__ __launch_bounds__(256) void k4_logits(
    const float* __restrict__ pe, const float* __restrict__ lq,
    const int* __restrict__ lp, float* __restrict__ eout, float* __restrict__ psum,
    int splits4, int rpb4) {
  int b = blockIdx.y, sp = blockIdx.x, tid = threadIdx.x;
  __shared__ float4 lqs4[32];
  __shared__ float red[4];
  if (tid < 32) lqs4[tid] = ((const float4*)(lq + b*HH))[tid];
  __syncthreads();
  int last = lp[b];
  int r0 = sp*rpb4, r1 = min(r0+rpb4, NN);
  int r = tid>>3, o = tid&7;
  const float4* peg = (const float4*)pe;
  float mysum = 0.f;
  for (int base = r0; base < r1; base += 64) {
    int nA = base + r, nB = base + 32 + r;
    bool vA = nA < r1, vB = nB < r1;
    long offA = (long)(b*NN + (vA ? nA : r1-1)) * 32;
    long offB = (long)(b*NN + (vB ? nB : r1-1)) * 32;
    float4 a4[4], b4[4];
    #pragma unroll
    for (int t = 0; t < 4; t++) { a4[t] = peg[offA + o + 8*t]; b4[t] = peg[offB + o + 8*t]; }
    float accA = 0.f, accB = 0.f;
    #pragma unroll
    for (int t = 0; t < 4; t++) {
      float4 k4 = lqs4[o + 8*t];
      accA += a4[t].x*k4.x + a4[t].y*k4.y + a4[t].z*k4.z + a4[t].w*k4.w;
      accB += b4[t].x*k4.x + b4[t].y*k4.y + b4[t].z*k4.z + b4[t].w*k4.w;
    }
    #pragma unroll
    for (int d = 1; d < 8; d <<= 1) {
      accA += __shfl_xor(accA, d);
      accB += __shfl_xor(accB, d);
    }
    if (o == 0) {
      if (vA) {
        float e = (nA == last) ? 0.f : __expf(10.f*tanhf(accA) - 10.f);
        eout[b*NN + nA] = e;
        mysum += e;
      }
      if (vB) {
        float e = (nB == last) ? 0.f : __expf(10.f*tanhf(accB) - 10.f);
        eout[b*NN + nB] = e;
        mysum += e;
      }
    }
  }
  #pragma unroll
  for (int d = 1; d < 64; d <<= 1) mysum += __shfl_xor(mysum, d);
  int w = tid>>6;
  if ((tid&63) == 0) red[w] = mysum;
  __syncthreads();
  if (tid == 0) psum[b*splits4+sp] = red[0]+red[1]+red[2]+red[3];
}

// ---------------- K5: scale ----------------
__global__ __launch_bounds__(256) void k5_scale(
    const float* __restrict__ eout, const float* __restrict__ psum,
    float* __restrict__ out, int splits4) {
  int b = blockIdx.y, sp = blockIdx.x, tid = threadIdx.x;
  __shared__ float S;
  if (tid == 0) {
    float a = 0.f;
    for (int s = 0; s < splits4; s++) a += psum[b*splits4+s];
    S = a;
  }
  __syncthreads();
  float inv = 1.f / S;
  int per = (NN + gridDim.x - 1) / gridDim.x;
  int lo = sp*per, hi = min(lo+per, NN);
  for (int n = lo + tid; n < hi; n += 256)
    out[b*NN + n] = eout[b*NN + n] * inv;
}

extern "C" void kernel_launch(void* const* d_in, const int* in_sizes, int n_in,
                              void* d_out, int out_size, void* d_ws, size_t ws_size,
                              hipStream_t stream) {
  const float* pe   = (const float*)d_in[0];
  const float* cls  = (const float*)d_in[1];
  const float* Wqg  = (const float*)d_in[2];
  const float* Wqf  = (const float*)d_in[3];
  const float* Wql  = (const float*)d_in[4];
  const float* Wk   = (const float*)d_in[5];
  const float* Wv   = (const float*)d_in[6];
  const float* lWk  = (const float*)d_in[7];
  const float* Wc   = (const float*)d_in[8];
  const float* bc   = (const float*)d_in[9];
  const int*   lp   = (const int*)d_in[10];
  float* out = (float*)d_out;
  float* ws  = (float*)d_ws;

  // choose k2 split count by workspace size
  int S2 = 32;
  {
    size_t need = (size_t)(65536 + BB*32*NHEAD + (size_t)BB*32*NHEAD*HH
                           + BB*NHEAD*HH + BB*HH + BB*NN + BB*32) * 4;
    if (ws_size < need) S2 = 8;
  }
  int rpb = (NN + S2 - 1) / S2;
  const int S4 = 32, rpb4 = (NN + S4 - 1) / S4;

  float* qk    = ws;
  float* lpart = qk + BB*NHEAD*HH;
  float* Wpart = lpart + BB*S2*NHEAD;
  float* Wn    = Wpart + (size_t)BB*S2*NHEAD*HH;
  float* lq    = Wn + BB*NHEAD*HH;
  float* eout  = lq + BB*HH;
  float* psum  = eout + BB*NN;

  k1_prep<<<dim3(BB), dim3(128), 0, stream>>>(pe, cls, Wqg, Wqf, Wql, Wk, lp, qk);
  k2_attn<<<dim3(S2, BB), dim3(256), 0, stream>>>(pe, qk, lp, lpart, Wpart, S2, rpb);
  k3a<<<dim3(BB, NHEAD), dim3(128), 0, stream>>>(lpart, Wpart, Wn, S2);
  k3b<<<dim3(BB), dim3(128), 0, stream>>>(Wn, Wv, Wc, bc, lWk, lq);
  k4_logits<<<dim3(S4, BB), dim3(256), 0, stream>>>(pe, lq, lp, eout, psum, S4, rpb4);
  k5_scale<<<dim3(8, BB), dim3(256), 0, stream>>>(eout, psum, out, S4);
}